// Round 8
// baseline (2378.835 us; speedup 1.0000x reference)
//
#include <hip/hip_runtime.h>
#include <cstdint>
#include <cstddef>

#define BB 64
#define TT 512
#define II 256
#define HH 256
#define GG 768   // 3*H

typedef _Float16 f16x2 __attribute__((ext_vector_type(2)));
typedef _Float16 f16x8 __attribute__((ext_vector_type(8)));
typedef float    f32x4 __attribute__((ext_vector_type(4)));

__device__ __forceinline__ float sigf(float x)       { return 1.f / (1.f + __expf(-x)); }
__device__ __forceinline__ float tanh_fast(float x)  { return 1.f - 2.f / (__expf(2.f * x) + 1.f); }

__device__ __forceinline__ uint32_t packf16(float a, float b) {
    f16x2 v; v.x = (_Float16)a; v.y = (_Float16)b;
    return __builtin_bit_cast(uint32_t, v);
}
__device__ __forceinline__ float cvt16(uint32_t u) {
    return (float)__builtin_bit_cast(_Float16, (unsigned short)(u & 0xffffu));
}

// ---------------------------------------------------------------------------
// Kernel A: pack Wh as MFMA B-fragments for the scan.
// Scan thread tid (0..511): w=tid>>6, l=tid&63, lr=l&15, lg=l>>4.
// For (G,rt,kt): frag elem e = Wh[rho][k], rho = 256G + 32w + 16rt + lr,
// k = 32kt + 8lg + e.  Stored as uint4 at wpk2[(d*48 + (G*2+rt)*8 + kt)*512 + tid].
// ---------------------------------------------------------------------------
__global__ void pack_wh2(const float* __restrict__ Whf,
                         const float* __restrict__ Whb,
                         uint4* __restrict__ wpk2)
{
    int idx = blockIdx.x * 256 + threadIdx.x;   // 0 .. 49151
    int d = idx / (48 * 512);
    int rem = idx - d * 48 * 512;
    int ntkt = rem >> 9;                        // 0..47
    int t = rem & 511;
    int nt = ntkt >> 3, kt = ntkt & 7;
    int G = nt >> 1, rt = nt & 1;
    int w = t >> 6, l = t & 63, lr = l & 15, lg = l >> 4;
    int rho = 256 * G + 32 * w + 16 * rt + lr;
    int k = 32 * kt + 8 * lg;
    const float* __restrict__ W = d ? Whb : Whf;
    const float* p = &W[(size_t)rho * II + k];
    uint4 v;
    v.x = packf16(p[0], p[1]);
    v.y = packf16(p[2], p[3]);
    v.z = packf16(p[4], p[5]);
    v.w = packf16(p[6], p[7]);
    wpk2[idx] = v;
}

// ---------------------------------------------------------------------------
// Kernel B: MFMA f16 GEMM for gi, writing f16 col-pair-packed output with
// bias folded: gi2[m][col-pair] = f16x2( x.Wi + bi + (G<2 ? bh : 0) ).
// (bh of the n-gate must stay separate: it sits inside r*hn in the cell.)
// gi2 row = 384 u32.  M = 65536, N = 768, K = 256; tile 64x64, BK=64.
// ---------------------------------------------------------------------------
__global__ __launch_bounds__(256) void gi_gemm_mfma2(
    const float* __restrict__ x,
    const float* __restrict__ Wif, const float* __restrict__ bif,
    const float* __restrict__ Wib, const float* __restrict__ bib,
    const float* __restrict__ bhf, const float* __restrict__ bhb,
    uint32_t* __restrict__ gi2)
{
    __shared__ __align__(16) _Float16 Asm[8][64][8];   // 8 KB
    __shared__ __align__(16) _Float16 Bsm[8][64][8];   // 8 KB

    const int ntile = blockIdx.x % 12;
    const int mtile = blockIdx.x / 12;
    const int m0 = mtile * 64;
    const int n0 = ntile * 64;
    const int d  = m0 >> 15;
    const int xrow0 = m0 & 32767;
    const float* __restrict__ W      = d ? Wib : Wif;
    const float* __restrict__ bias_i = d ? bib : bif;
    const float* __restrict__ bias_h = d ? bhb : bhf;

    const int tid  = threadIdx.x;
    const int w    = tid >> 6;
    const int lane = tid & 63;
    const int lr   = lane & 15;
    const int lk8  = (lane >> 4);

    f32x4 acc[4] = {};

    const int srow = tid >> 2;
    const int scol = (tid & 3) * 16;

    for (int k0 = 0; k0 < II; k0 += 64) {
        const float* ap = &x[(size_t)(xrow0 + srow) * II + k0 + scol];
        const float* bp = &W[(size_t)(n0 + srow)   * II + k0 + scol];
#pragma unroll
        for (int half = 0; half < 2; ++half) {
            float4 a0 = *(const float4*)(ap + 8 * half);
            float4 a1 = *(const float4*)(ap + 8 * half + 4);
            float4 b0 = *(const float4*)(bp + 8 * half);
            float4 b1 = *(const float4*)(bp + 8 * half + 4);
            f16x8 av, bv;
            av[0] = (_Float16)a0.x; av[1] = (_Float16)a0.y;
            av[2] = (_Float16)a0.z; av[3] = (_Float16)a0.w;
            av[4] = (_Float16)a1.x; av[5] = (_Float16)a1.y;
            av[6] = (_Float16)a1.z; av[7] = (_Float16)a1.w;
            bv[0] = (_Float16)b0.x; bv[1] = (_Float16)b0.y;
            bv[2] = (_Float16)b0.z; bv[3] = (_Float16)b0.w;
            bv[4] = (_Float16)b1.x; bv[5] = (_Float16)b1.y;
            bv[6] = (_Float16)b1.z; bv[7] = (_Float16)b1.w;
            *(f16x8*)&Asm[scol / 8 + half][srow][0] = av;
            *(f16x8*)&Bsm[scol / 8 + half][srow][0] = bv;
        }
        __syncthreads();

#pragma unroll
        for (int kk = 0; kk < 2; ++kk) {
            const int kb = kk * 4 + lk8;
            f16x8 af = *(const f16x8*)&Asm[kb][16 * w + lr][0];
#pragma unroll
            for (int j = 0; j < 4; ++j) {
                f16x8 bf = *(const f16x8*)&Bsm[kb][16 * j + lr][0];
                acc[j] = __builtin_amdgcn_mfma_f32_16x16x32_f16(af, bf, acc[j], 0, 0, 0);
            }
        }
        __syncthreads();
    }

    // epilogue: add bi (+bh for r,z gates), pack col-pairs f16x2, store u32.
    const int rbase = m0 + 16 * w + (lane >> 4) * 4;
#pragma unroll
    for (int j = 0; j < 4; ++j) {
        const int col = n0 + 16 * j + lr;
        float bsum = bias_i[col] + ((n0 < 512) ? bias_h[col] : 0.f);
#pragma unroll
        for (int r = 0; r < 4; ++r) {
            float v  = acc[j][r] + bsum;
            float vn = __shfl_down(v, 1);
            if (!(lane & 1)) {
                gi2[(size_t)(rbase + r) * 384 + (col >> 1)] = packf16(v, vn);
            }
        }
    }
}

// ---------------------------------------------------------------------------
// Kernel C: MFMA scan.  8 WGs x 512 threads (2 waves/SIMD).
// WG g: d=g>>2, chains cb=(g&3)*16 .. +16 (batch rows, one direction).
// Wave w owns cols [32w,32w+32) of each gate region.  Per step:
//   gh[16][768-slice] = h[16][256] @ Wh^T via 48 mfma_16x16x32_f16/wave,
//   A (=h) from LDS hA (f16, stride-280 rows: 16B-aligned + 2-way banks only),
//   B (=Wh) register-resident (192 VGPRs), C/D: col=lane&15, row=(lane>>4)*4+r
//   -> r/z/n accumulators for output (chain m, col o) are in the SAME lane,
//   gates fully in-register; h_prev in regs; gi2 prefetched 1 step (12 u32).
// ONE barrier per step.
// ---------------------------------------------------------------------------
__global__ __launch_bounds__(512, 2) void gru_scan_mfma(
    const uint32_t* __restrict__ gi2,   // [2*64][512][384] u32 (f16x2 col-pairs)
    const uint4* __restrict__ wpk2,     // [2][48][512] uint4
    const float* __restrict__ h0f, const float* __restrict__ h0b,
    const float* __restrict__ bhf, const float* __restrict__ bhb,
    float* __restrict__ out)
{
    __shared__ __align__(16) _Float16 hA[2][16][280];   // 17.9 KB

    const int g   = blockIdx.x;
    const int d   = g >> 2;
    const int cb  = (g & 3) << 4;
    const int tid = threadIdx.x;
    const int w   = tid >> 6;
    const int l   = tid & 63;
    const int lr  = l & 15;
    const int lg  = l >> 4;

    const float* __restrict__ bh = d ? bhb : bhf;
    const float* __restrict__ h0 = d ? h0b : h0f;

    // ---- B fragments (one-time, coalesced dwordx4) ----
    f16x8 wB[3][2][8];
    {
        const uint4* wp = wpk2 + (size_t)d * (48 * 512);
#pragma unroll
        for (int G = 0; G < 3; ++G)
#pragma unroll
        for (int rt = 0; rt < 2; ++rt)
#pragma unroll
        for (int kt = 0; kt < 8; ++kt) {
            uint4 v = wp[(size_t)(((G * 2 + rt) * 8 + kt) * 512) + tid];
            wB[G][rt][kt] = __builtin_bit_cast(f16x8, v);
        }
    }

    // n-gate recurrent bias (kept out of the GEMM fold)
    float bbn[2];
#pragma unroll
    for (int rt = 0; rt < 2; ++rt) bbn[rt] = bh[512 + 32 * w + 16 * rt + lr];

    // ---- h0 into regs + hA[0] ----
    float hp[2][4];
#pragma unroll
    for (int rt = 0; rt < 2; ++rt)
#pragma unroll
    for (int r = 0; r < 4; ++r)
        hp[rt][r] = h0[(size_t)(cb + 4 * lg + r) * HH + 32 * w + 16 * rt + lr];

#pragma unroll
    for (int rt = 0; rt < 2; ++rt)
#pragma unroll
    for (int r = 0; r < 4; ++r) {
        float v  = hp[rt][r];
        float vn = __shfl_down(v, 1);
        if (!(l & 1)) {
            ((uint32_t*)&hA[0][4 * lg + r][0])[(32 * w + 16 * rt + lr) >> 1] =
                packf16(v, vn);
        }
    }

    const int dir = d ? -1 : 1;
    int ta = d ? (TT - 1) : 0;
    const uint32_t* g2 = gi2 + ((size_t)(d * 64 + cb) * TT + ta) * 384;
    const int shf = (l & 1) * 16;

    // gi prefetch (12 u32 = 24 f16 values: 8 outputs x 3 gates)
    uint32_t gvp[2][4][3];
#pragma unroll
    for (int rt = 0; rt < 2; ++rt)
#pragma unroll
    for (int r = 0; r < 4; ++r)
#pragma unroll
    for (int G = 0; G < 3; ++G)
        gvp[rt][r][G] = g2[(size_t)(4 * lg + r) * 196608 +
                           128 * G + 16 * w + 8 * rt + (lr >> 1)];

    __syncthreads();

    for (int s = 0; s < TT; ++s) {
        const int cur = s & 1;

        f32x4 acc[3][2] = {};
#pragma unroll
        for (int kt = 0; kt < 8; ++kt) {
            f16x8 Af = *(const f16x8*)&hA[cur][lr][32 * kt + 8 * lg];
#pragma unroll
            for (int G = 0; G < 3; ++G)
#pragma unroll
            for (int rt = 0; rt < 2; ++rt)
                acc[G][rt] = __builtin_amdgcn_mfma_f32_16x16x32_f16(
                    Af, wB[G][rt][kt], acc[G][rt], 0, 0, 0);
        }

        // ---- gates: fully in-register ----
#pragma unroll
        for (int rt = 0; rt < 2; ++rt) {
#pragma unroll
            for (int r = 0; r < 4; ++r) {
                float ir  = cvt16(gvp[rt][r][0] >> shf);
                float iz  = cvt16(gvp[rt][r][1] >> shf);
                float inn = cvt16(gvp[rt][r][2] >> shf);
                float hr = acc[0][rt][r];
                float hz = acc[1][rt][r];
                float hn = acc[2][rt][r] + bbn[rt];
                float rg = sigf(ir + hr);
                float zg = sigf(iz + hz);
                float ng = tanh_fast(fmaf(rg, hn, inn));
                float hnew = tanh_fast(fmaf(zg, hp[rt][r] - ng, ng));
                hp[rt][r] = hnew;
                out[((size_t)(cb + 4 * lg + r) * TT + ta) * (2 * HH) +
                    d * HH + 32 * w + 16 * rt + lr] = hnew;
            }
        }

        // ---- write next h buffer (f16 pairs, even lanes) ----
#pragma unroll
        for (int rt = 0; rt < 2; ++rt)
#pragma unroll
        for (int r = 0; r < 4; ++r) {
            float v  = hp[rt][r];
            float vn = __shfl_down(v, 1);
            if (!(l & 1)) {
                ((uint32_t*)&hA[cur ^ 1][4 * lg + r][0])[(32 * w + 16 * rt + lr) >> 1] =
                    packf16(v, vn);
            }
        }

        // ---- prefetch next step's gi (in flight across the barrier) ----
        ta += dir;
        if (s + 1 < TT) {
            g2 += (ptrdiff_t)dir * 384;
#pragma unroll
            for (int rt = 0; rt < 2; ++rt)
#pragma unroll
            for (int r = 0; r < 4; ++r)
#pragma unroll
            for (int G = 0; G < 3; ++G)
                gvp[rt][r][G] = g2[(size_t)(4 * lg + r) * 196608 +
                                   128 * G + 16 * w + 8 * rt + (lr >> 1)];
        }
        __syncthreads();
    }
}

// ---------------------------------------------------------------------------
// Fallback scan (ws too small): unchanged known-good path.
// ---------------------------------------------------------------------------
__global__ __launch_bounds__(768) void gru_scan_fallback(
    const float* __restrict__ x,
    const float* __restrict__ h0f, const float* __restrict__ h0b,
    const float* __restrict__ Wif, const float* __restrict__ bif_,
    const float* __restrict__ Whf, const float* __restrict__ bhf,
    const float* __restrict__ Wib, const float* __restrict__ bib_,
    const float* __restrict__ Whb, const float* __restrict__ bhb,
    float* __restrict__ out)
{
    __shared__ __align__(16) float hbuf[2][HH];
    __shared__ float gh_s[GG];
    __shared__ float gi_s[GG];
    __shared__ __align__(16) float xrow[II];

    const int bx  = blockIdx.x;
    const int d   = bx >> 6;
    const int b   = bx & 63;
    const int tid = threadIdx.x;

    const float* __restrict__ Wh = d ? Whb : Whf;
    const float* __restrict__ bh = d ? bhb : bhf;
    const float* __restrict__ Wi = d ? Wib : Wif;
    const float* __restrict__ bi = d ? bib_ : bif_;
    const float* __restrict__ h0 = d ? h0b : h0f;

    if (tid < HH) hbuf[0][tid] = h0[(size_t)b * HH + tid];

    const float bh_row = bh[tid];
    const float bi_row = bi[tid];
    const float4* __restrict__ whr = (const float4*)(Wh + (size_t)tid * II);
    const float4* __restrict__ wir = (const float4*)(Wi + (size_t)tid * II);

    __syncthreads();

    for (int s = 0; s < TT; ++s) {
        const int ta  = d ? (TT - 1 - s) : s;
        const int cur = s & 1;

        if (tid < II) xrow[tid] = x[((size_t)b * TT + ta) * II + tid];
        __syncthreads();

        const float4* hv4 = (const float4*)hbuf[cur];
        float a0 = 0.f, a1 = 0.f, a2 = 0.f, a3 = 0.f;
#pragma unroll 4
        for (int k = 0; k < II / 4; k += 4) {
            float4 w0 = whr[k], w1 = whr[k + 1], w2 = whr[k + 2], w3 = whr[k + 3];
            float4 q0 = hv4[k], q1 = hv4[k + 1], q2 = hv4[k + 2], q3 = hv4[k + 3];
            a0 += w0.x * q0.x + w0.y * q0.y + w0.z * q0.z + w0.w * q0.w;
            a1 += w1.x * q1.x + w1.y * q1.y + w1.z * q1.z + w1.w * q1.w;
            a2 += w2.x * q2.x + w2.y * q2.y + w2.z * q2.z + w2.w * q2.w;
            a3 += w3.x * q3.x + w3.y * q3.y + w3.z * q3.z + w3.w * q3.w;
        }
        gh_s[tid] = (a0 + a1) + (a2 + a3) + bh_row;

        const float4* xv4 = (const float4*)xrow;
        float c0 = 0.f, c1 = 0.f, c2 = 0.f, c3 = 0.f;
#pragma unroll 4
        for (int k = 0; k < II / 4; k += 4) {
            float4 w0 = wir[k], w1 = wir[k + 1], w2 = wir[k + 2], w3 = wir[k + 3];
            float4 q0 = xv4[k], q1 = xv4[k + 1], q2 = xv4[k + 2], q3 = xv4[k + 3];
            c0 += w0.x * q0.x + w0.y * q0.y + w0.z * q0.z + w0.w * q0.w;
            c1 += w1.x * q1.x + w1.y * q1.y + w1.z * q1.z + w1.w * q1.w;
            c2 += w2.x * q2.x + w2.y * q2.y + w2.z * q2.z + w2.w * q2.w;
            c3 += w3.x * q3.x + w3.y * q3.y + w3.z * q3.z + w3.w * q3.w;
        }
        gi_s[tid] = (c0 + c1) + (c2 + c3) + bi_row;
        __syncthreads();

        if (tid < HH) {
            float ir = gi_s[tid], iz = gi_s[HH + tid], inn = gi_s[2 * HH + tid];
            float hr = gh_s[tid], hz = gh_s[HH + tid], hn = gh_s[2 * HH + tid];
            float r  = sigf(ir + hr);
            float z  = sigf(iz + hz);
            float n  = tanh_fast(inn + r * hn);
            float hp = hbuf[cur][tid];
            float hnew = tanh_fast((1.f - z) * n + z * hp);
            hbuf[cur ^ 1][tid] = hnew;
            out[((size_t)b * TT + ta) * (2 * HH) + d * HH + tid] = hnew;
        }
        __syncthreads();
    }
}

// ---------------------------------------------------------------------------
extern "C" void kernel_launch(void* const* d_in, const int* in_sizes, int n_in,
                              void* d_out, int out_size, void* d_ws, size_t ws_size,
                              hipStream_t stream)
{
    const float* x   = (const float*)d_in[0];
    const float* h0f = (const float*)d_in[1];
    const float* h0b = (const float*)d_in[2];
    const float* Wif = (const float*)d_in[3];
    const float* Whf = (const float*)d_in[4];
    const float* bif = (const float*)d_in[5];
    const float* bhf = (const float*)d_in[6];
    const float* Wib = (const float*)d_in[7];
    const float* Whb = (const float*)d_in[8];
    const float* bib = (const float*)d_in[9];
    const float* bhb = (const float*)d_in[10];
    float* out = (float*)d_out;

    const size_t gi2_bytes  = (size_t)2 * BB * TT * 384 * sizeof(uint32_t); // 100,663,296
    const size_t wpk2_bytes = (size_t)2 * 48 * 512 * sizeof(uint4);         //     786,432

    if (ws_size >= gi2_bytes + wpk2_bytes) {
        uint32_t* gi2  = (uint32_t*)d_ws;
        uint4*    wpk2p = (uint4*)((char*)d_ws + gi2_bytes);

        pack_wh2<<<192, 256, 0, stream>>>(Whf, Whb, wpk2p);

        gi_gemm_mfma2<<<12288, 256, 0, stream>>>(x, Wif, bif, Wib, bib,
                                                 bhf, bhb, gi2);

        gru_scan_mfma<<<8, 512, 0, stream>>>(gi2, wpk2p, h0f, h0b, bhf, bhb, out);
    } else {
        gru_scan_fallback<<<128, 768, 0, stream>>>(
            x, h0f, h0b, Wif, bif, Whf, bhf, Wib, bib, Whb, bhb, out);
    }
}

// Round 9
// 818.338 us; speedup vs baseline: 2.9069x; 2.9069x over previous
//
#include <hip/hip_runtime.h>
#include <cstdint>
#include <cstddef>

#define BB 64
#define TT 512
#define II 256
#define HH 256
#define GG 768   // 3*H

typedef _Float16 f16x2 __attribute__((ext_vector_type(2)));
typedef _Float16 f16x8 __attribute__((ext_vector_type(8)));
typedef float    f32x4 __attribute__((ext_vector_type(4)));

__device__ __forceinline__ float sigf(float x)       { return 1.f / (1.f + __expf(-x)); }
__device__ __forceinline__ float tanh_fast(float x)  { return 1.f - 2.f / (__expf(2.f * x) + 1.f); }

__device__ __forceinline__ uint32_t packf16(float a, float b) {
    f16x2 v; v.x = (_Float16)a; v.y = (_Float16)b;
    return __builtin_bit_cast(uint32_t, v);
}
__device__ __forceinline__ float cvt16(uint32_t u) {
    return (float)__builtin_bit_cast(_Float16, (unsigned short)(u & 0xffffu));
}

// ---------------------------------------------------------------------------
// Kernel A: pack Wh as MFMA B-fragments (byte-identical to R8, verified).
// Scan thread tid (0..511): w=tid>>6, l=tid&63, lr=l&15, lg=l>>4.
// For (G,rt,kt): frag elem e = Wh[rho][k], rho = 256G + 32w + 16rt + lr,
// k = 32kt + 8lg + e.  Stored as uint4 at wpk2[(d*48 + (G*2+rt)*8 + kt)*512 + tid].
// ---------------------------------------------------------------------------
__global__ void pack_wh2(const float* __restrict__ Whf,
                         const float* __restrict__ Whb,
                         uint4* __restrict__ wpk2)
{
    int idx = blockIdx.x * 256 + threadIdx.x;   // 0 .. 49151
    int d = idx / (48 * 512);
    int rem = idx - d * 48 * 512;
    int ntkt = rem >> 9;                        // 0..47
    int t = rem & 511;
    int nt = ntkt >> 3, kt = ntkt & 7;
    int G = nt >> 1, rt = nt & 1;
    int w = t >> 6, l = t & 63, lr = l & 15, lg = l >> 4;
    int rho = 256 * G + 32 * w + 16 * rt + lr;
    int k = 32 * kt + 8 * lg;
    const float* __restrict__ W = d ? Whb : Whf;
    const float* p = &W[(size_t)rho * II + k];
    uint4 v;
    v.x = packf16(p[0], p[1]);
    v.y = packf16(p[2], p[3]);
    v.z = packf16(p[4], p[5]);
    v.w = packf16(p[6], p[7]);
    wpk2[idx] = v;
}

// ---------------------------------------------------------------------------
// Kernel B: MFMA f16 GEMM for gi (byte-identical to R8, verified).
// gi2[m][col-pair] = f16x2( x.Wi + bi + (G<2 ? bh : 0) ), row = 384 u32.
// ---------------------------------------------------------------------------
__global__ __launch_bounds__(256) void gi_gemm_mfma2(
    const float* __restrict__ x,
    const float* __restrict__ Wif, const float* __restrict__ bif,
    const float* __restrict__ Wib, const float* __restrict__ bib,
    const float* __restrict__ bhf, const float* __restrict__ bhb,
    uint32_t* __restrict__ gi2)
{
    __shared__ __align__(16) _Float16 Asm[8][64][8];   // 8 KB
    __shared__ __align__(16) _Float16 Bsm[8][64][8];   // 8 KB

    const int ntile = blockIdx.x % 12;
    const int mtile = blockIdx.x / 12;
    const int m0 = mtile * 64;
    const int n0 = ntile * 64;
    const int d  = m0 >> 15;
    const int xrow0 = m0 & 32767;
    const float* __restrict__ W      = d ? Wib : Wif;
    const float* __restrict__ bias_i = d ? bib : bif;
    const float* __restrict__ bias_h = d ? bhb : bhf;

    const int tid  = threadIdx.x;
    const int w    = tid >> 6;
    const int lane = tid & 63;
    const int lr   = lane & 15;
    const int lk8  = (lane >> 4);

    f32x4 acc[4] = {};

    const int srow = tid >> 2;
    const int scol = (tid & 3) * 16;

    for (int k0 = 0; k0 < II; k0 += 64) {
        const float* ap = &x[(size_t)(xrow0 + srow) * II + k0 + scol];
        const float* bp = &W[(size_t)(n0 + srow)   * II + k0 + scol];
#pragma unroll
        for (int half = 0; half < 2; ++half) {
            float4 a0 = *(const float4*)(ap + 8 * half);
            float4 a1 = *(const float4*)(ap + 8 * half + 4);
            float4 b0 = *(const float4*)(bp + 8 * half);
            float4 b1 = *(const float4*)(bp + 8 * half + 4);
            f16x8 av, bv;
            av[0] = (_Float16)a0.x; av[1] = (_Float16)a0.y;
            av[2] = (_Float16)a0.z; av[3] = (_Float16)a0.w;
            av[4] = (_Float16)a1.x; av[5] = (_Float16)a1.y;
            av[6] = (_Float16)a1.z; av[7] = (_Float16)a1.w;
            bv[0] = (_Float16)b0.x; bv[1] = (_Float16)b0.y;
            bv[2] = (_Float16)b0.z; bv[3] = (_Float16)b0.w;
            bv[4] = (_Float16)b1.x; bv[5] = (_Float16)b1.y;
            bv[6] = (_Float16)b1.z; bv[7] = (_Float16)b1.w;
            *(f16x8*)&Asm[scol / 8 + half][srow][0] = av;
            *(f16x8*)&Bsm[scol / 8 + half][srow][0] = bv;
        }
        __syncthreads();

#pragma unroll
        for (int kk = 0; kk < 2; ++kk) {
            const int kb = kk * 4 + lk8;
            f16x8 af = *(const f16x8*)&Asm[kb][16 * w + lr][0];
#pragma unroll
            for (int j = 0; j < 4; ++j) {
                f16x8 bf = *(const f16x8*)&Bsm[kb][16 * j + lr][0];
                acc[j] = __builtin_amdgcn_mfma_f32_16x16x32_f16(af, bf, acc[j], 0, 0, 0);
            }
        }
        __syncthreads();
    }

    const int rbase = m0 + 16 * w + (lane >> 4) * 4;
#pragma unroll
    for (int j = 0; j < 4; ++j) {
        const int col = n0 + 16 * j + lr;
        float bsum = bias_i[col] + ((n0 < 512) ? bias_h[col] : 0.f);
#pragma unroll
        for (int r = 0; r < 4; ++r) {
            float v  = acc[j][r] + bsum;
            float vn = __shfl_down(v, 1);
            if (!(lane & 1)) {
                gi2[(size_t)(rbase + r) * 384 + (col >> 1)] = packf16(v, vn);
            }
        }
    }
}

// ---------------------------------------------------------------------------
// Kernel C: MFMA scan in the 128-WG shell.  1 chain per WG, 512 threads
// (8 waves, 2/SIMD).  A-BROADCAST: every 16-lane group reads the SAME 16 B
// of h from LDS -> all 16 A-rows equal h -> every D row equals gh (the 16x
// M-redundancy rides the otherwise-idle MFMA pipe).  Wave w owns cols
// [32w,32w+32) of each of the 3 gate regions: 6 accumulators; r/z/n for an
// output col land in the same lane.  Gates on lanes<16; h_prev in regs;
// hA = 1KB double-buffered f16 vector; ONE barrier/step.
// ---------------------------------------------------------------------------
__global__ __launch_bounds__(512, 2) void gru_scan_mfma2(
    const uint32_t* __restrict__ gi2,   // [2*64][512][384] u32 (f16x2 col-pairs)
    const uint4* __restrict__ wpk2,     // [2][48][512] uint4
    const float* __restrict__ h0f, const float* __restrict__ h0b,
    const float* __restrict__ bhf, const float* __restrict__ bhb,
    float* __restrict__ out)
{
    __shared__ __align__(16) _Float16 hA[2][264];   // 2 x 528 B

    const int bx  = blockIdx.x;
    const int d   = bx >> 6;
    const int b   = bx & 63;
    const int tid = threadIdx.x;
    const int w   = tid >> 6;
    const int l   = tid & 63;
    const int lr  = l & 15;
    const int lg  = l >> 4;

    const float* __restrict__ bh = d ? bhb : bhf;
    const float* __restrict__ h0 = d ? h0b : h0f;

    // ---- B fragments (one-time, coalesced dwordx4; layout as pack_wh2) ----
    f16x8 wB[3][2][8];
    {
        const uint4* wp = wpk2 + (size_t)d * (48 * 512);
#pragma unroll
        for (int G = 0; G < 3; ++G)
#pragma unroll
        for (int rt = 0; rt < 2; ++rt)
#pragma unroll
        for (int kt = 0; kt < 8; ++kt) {
            uint4 v = wp[(size_t)(((G * 2 + rt) * 8 + kt) * 512) + tid];
            wB[G][rt][kt] = __builtin_bit_cast(f16x8, v);
        }
    }

    // n-gate recurrent bias (r/z bh folded into gi2 by the GEMM)
    float bbn[2];
#pragma unroll
    for (int rt = 0; rt < 2; ++rt) bbn[rt] = bh[512 + 32 * w + 16 * rt + lr];

    // ---- h0 into regs (lanes<16 own cols 32w+16rt+lr) + hA[0] ----
    float hp[2];
#pragma unroll
    for (int rt = 0; rt < 2; ++rt)
        hp[rt] = h0[(size_t)b * HH + 32 * w + 16 * rt + lr];

    if (l < 16) {
#pragma unroll
        for (int rt = 0; rt < 2; ++rt) {
            float v  = hp[rt];
            float vn = __shfl_down(v, 1);
            if (!(lr & 1))
                ((uint32_t*)hA[0])[(32 * w + 16 * rt + lr) >> 1] = packf16(v, vn);
        }
    }

    const int dir = d ? -1 : 1;
    int ta = d ? (TT - 1) : 0;
    const uint32_t* g2 = gi2 + ((size_t)(d * 64 + b) * TT + ta) * 384;
    const int shf = (lr & 1) * 16;

    // gi prefetch: 6 u32 (3 gates x 2 col-tiles), lanes<16 consume
    uint32_t gvp[3][2];
#pragma unroll
    for (int G = 0; G < 3; ++G)
#pragma unroll
    for (int rt = 0; rt < 2; ++rt)
        gvp[G][rt] = g2[128 * G + ((32 * w + 16 * rt + lr) >> 1)];

    __syncthreads();

    for (int s = 0; s < TT; ++s) {
        const int cur = s & 1;

        // ---- MFMA phase: 48 mfma/wave, A = broadcast h (conflict-free) ----
        f32x4 acc[3][2] = {};
#pragma unroll
        for (int kt = 0; kt < 8; ++kt) {
            f16x8 Af = *(const f16x8*)&hA[cur][32 * kt + 8 * lg];
#pragma unroll
            for (int G = 0; G < 3; ++G)
#pragma unroll
            for (int rt = 0; rt < 2; ++rt)
                acc[G][rt] = __builtin_amdgcn_mfma_f32_16x16x32_f16(
                    Af, wB[G][rt][kt], acc[G][rt], 0, 0, 0);
        }

        // ---- update (lanes<16): gates in-register, col = 32w+16rt+lr ----
        if (l < 16) {
            float ir[2], iz[2], inn[2];
#pragma unroll
            for (int rt = 0; rt < 2; ++rt) {
                ir[rt]  = cvt16(gvp[0][rt] >> shf);
                iz[rt]  = cvt16(gvp[1][rt] >> shf);
                inn[rt] = cvt16(gvp[2][rt] >> shf);
            }
            // prefetch next step's gi now: latency hides under gate math,
            // barrier, and next MFMA phase.
            if (s + 1 < TT) {
                g2 += (ptrdiff_t)dir * 384;
#pragma unroll
                for (int G = 0; G < 3; ++G)
#pragma unroll
                for (int rt = 0; rt < 2; ++rt)
                    gvp[G][rt] = g2[128 * G + ((32 * w + 16 * rt + lr) >> 1)];
            }
#pragma unroll
            for (int rt = 0; rt < 2; ++rt) {
                float hr = acc[0][rt][0];          // all D rows equal gh
                float hz = acc[1][rt][0];
                float hn = acc[2][rt][0] + bbn[rt];
                float rg = sigf(ir[rt] + hr);
                float zg = sigf(iz[rt] + hz);
                float ng = tanh_fast(fmaf(rg, hn, inn[rt]));
                float hnew = tanh_fast(fmaf(zg, hp[rt] - ng, ng));
                hp[rt] = hnew;
                out[((size_t)b * TT + ta) * (2 * HH) + d * HH +
                    32 * w + 16 * rt + lr] = hnew;
                float vn = __shfl_down(hnew, 1);
                if (!(lr & 1))
                    ((uint32_t*)hA[cur ^ 1])[(32 * w + 16 * rt + lr) >> 1] =
                        packf16(hnew, vn);
            }
        }
        ta += dir;
        __syncthreads();
    }
}

// ---------------------------------------------------------------------------
// Fallback scan (ws too small): unchanged known-good path.
// ---------------------------------------------------------------------------
__global__ __launch_bounds__(768) void gru_scan_fallback(
    const float* __restrict__ x,
    const float* __restrict__ h0f, const float* __restrict__ h0b,
    const float* __restrict__ Wif, const float* __restrict__ bif_,
    const float* __restrict__ Whf, const float* __restrict__ bhf,
    const float* __restrict__ Wib, const float* __restrict__ bib_,
    const float* __restrict__ Whb, const float* __restrict__ bhb,
    float* __restrict__ out)
{
    __shared__ __align__(16) float hbuf[2][HH];
    __shared__ float gh_s[GG];
    __shared__ float gi_s[GG];
    __shared__ __align__(16) float xrow[II];

    const int bx  = blockIdx.x;
    const int d   = bx >> 6;
    const int b   = bx & 63;
    const int tid = threadIdx.x;

    const float* __restrict__ Wh = d ? Whb : Whf;
    const float* __restrict__ bh = d ? bhb : bhf;
    const float* __restrict__ Wi = d ? Wib : Wif;
    const float* __restrict__ bi = d ? bib_ : bif_;
    const float* __restrict__ h0 = d ? h0b : h0f;

    if (tid < HH) hbuf[0][tid] = h0[(size_t)b * HH + tid];

    const float bh_row = bh[tid];
    const float bi_row = bi[tid];
    const float4* __restrict__ whr = (const float4*)(Wh + (size_t)tid * II);
    const float4* __restrict__ wir = (const float4*)(Wi + (size_t)tid * II);

    __syncthreads();

    for (int s = 0; s < TT; ++s) {
        const int ta  = d ? (TT - 1 - s) : s;
        const int cur = s & 1;

        if (tid < II) xrow[tid] = x[((size_t)b * TT + ta) * II + tid];
        __syncthreads();

        const float4* hv4 = (const float4*)hbuf[cur];
        float a0 = 0.f, a1 = 0.f, a2 = 0.f, a3 = 0.f;
#pragma unroll 4
        for (int k = 0; k < II / 4; k += 4) {
            float4 w0 = whr[k], w1 = whr[k + 1], w2 = whr[k + 2], w3 = whr[k + 3];
            float4 q0 = hv4[k], q1 = hv4[k + 1], q2 = hv4[k + 2], q3 = hv4[k + 3];
            a0 += w0.x * q0.x + w0.y * q0.y + w0.z * q0.z + w0.w * q0.w;
            a1 += w1.x * q1.x + w1.y * q1.y + w1.z * q1.z + w1.w * q1.w;
            a2 += w2.x * q2.x + w2.y * q2.y + w2.z * q2.z + w2.w * q2.w;
            a3 += w3.x * q3.x + w3.y * q3.y + w3.z * q3.z + w3.w * q3.w;
        }
        gh_s[tid] = (a0 + a1) + (a2 + a3) + bh_row;

        const float4* xv4 = (const float4*)xrow;
        float c0 = 0.f, c1 = 0.f, c2 = 0.f, c3 = 0.f;
#pragma unroll 4
        for (int k = 0; k < II / 4; k += 4) {
            float4 w0 = wir[k], w1 = wir[k + 1], w2 = wir[k + 2], w3 = wir[k + 3];
            float4 q0 = xv4[k], q1 = xv4[k + 1], q2 = xv4[k + 2], q3 = xv4[k + 3];
            c0 += w0.x * q0.x + w0.y * q0.y + w0.z * q0.z + w0.w * q0.w;
            c1 += w1.x * q1.x + w1.y * q1.y + w1.z * q1.z + w1.w * q1.w;
            c2 += w2.x * q2.x + w2.y * q2.y + w2.z * q2.z + w2.w * q2.w;
            c3 += w3.x * q3.x + w3.y * q3.y + w3.z * q3.z + w3.w * q3.w;
        }
        gi_s[tid] = (c0 + c1) + (c2 + c3) + bi_row;
        __syncthreads();

        if (tid < HH) {
            float ir = gi_s[tid], iz = gi_s[HH + tid], inn = gi_s[2 * HH + tid];
            float hr = gh_s[tid], hz = gh_s[HH + tid], hn = gh_s[2 * HH + tid];
            float r  = sigf(ir + hr);
            float z  = sigf(iz + hz);
            float n  = tanh_fast(inn + r * hn);
            float hp = hbuf[cur][tid];
            float hnew = tanh_fast((1.f - z) * n + z * hp);
            hbuf[cur ^ 1][tid] = hnew;
            out[((size_t)b * TT + ta) * (2 * HH) + d * HH + tid] = hnew;
        }
        __syncthreads();
    }
}

// ---------------------------------------------------------------------------
extern "C" void kernel_launch(void* const* d_in, const int* in_sizes, int n_in,
                              void* d_out, int out_size, void* d_ws, size_t ws_size,
                              hipStream_t stream)
{
    const float* x   = (const float*)d_in[0];
    const float* h0f = (const float*)d_in[1];
    const float* h0b = (const float*)d_in[2];
    const float* Wif = (const float*)d_in[3];
    const float* Whf = (const float*)d_in[4];
    const float* bif = (const float*)d_in[5];
    const float* bhf = (const float*)d_in[6];
    const float* Wib = (const float*)d_in[7];
    const float* Whb = (const float*)d_in[8];
    const float* bib = (const float*)d_in[9];
    const float* bhb = (const float*)d_in[10];
    float* out = (float*)d_out;

    const size_t gi2_bytes  = (size_t)2 * BB * TT * 384 * sizeof(uint32_t); // 100,663,296
    const size_t wpk2_bytes = (size_t)2 * 48 * 512 * sizeof(uint4);         //     786,432

    if (ws_size >= gi2_bytes + wpk2_bytes) {
        uint32_t* gi2   = (uint32_t*)d_ws;
        uint4*    wpk2p = (uint4*)((char*)d_ws + gi2_bytes);

        pack_wh2<<<192, 256, 0, stream>>>(Whf, Whb, wpk2p);

        gi_gemm_mfma2<<<12288, 256, 0, stream>>>(x, Wif, bif, Wib, bib,
                                                 bhf, bhb, gi2);

        gru_scan_mfma2<<<128, 512, 0, stream>>>(gi2, wpk2p, h0f, h0b, bhf, bhb, out);
    } else {
        gru_scan_fallback<<<128, 768, 0, stream>>>(
            x, h0f, h0b, Wif, bif, Whf, bhf, Wib, bib, Whb, bhb, out);
    }
}